// Round 1
// baseline (592.382 us; speedup 1.0000x reference)
//
#include <hip/hip_runtime.h>
#include <hip/hip_bf16.h>

#define STATE 16
#define DNA_C 4
#define HID   128
#define FAN1  52      // 16*3 + 4
#define HH    256
#define WW    256

__global__ __launch_bounds__(256) void update_net_f32(
    const float* __restrict__ x,    // [B,16,256,256]
    const float* __restrict__ dna,  // [B,4,256,256]
    const float* __restrict__ w1,   // [128,52]
    const float* __restrict__ w2,   // [16,128]
    float* __restrict__ out)        // [B,16,256,256]
{
    const int xw  = threadIdx.x;        // 0..255, W coordinate
    const int row = blockIdx.x;         // b*256 + y
    const int b   = row >> 8;
    const int y   = row & 255;

    const bool has_l = (xw > 0);
    const bool has_r = (xw < WW - 1);
    const bool has_t = (y > 0);
    const bool has_b = (y < HH - 1);

    float feat[FAN1];

    // ---- load x neighborhoods, compute Sobel (zero-pad SAME) ----
    #pragma unroll
    for (int c = 0; c < STATE; ++c) {
        const float* p = x + (((size_t)b * STATE + c) * HH + y) * WW + xw;
        float tl = 0.f, tc = 0.f, tr = 0.f;
        float ml = 0.f,           mr = 0.f;
        float bl = 0.f, bc = 0.f, br = 0.f;
        const float mc = p[0];
        if (has_l) ml = p[-1];
        if (has_r) mr = p[1];
        if (has_t) {
            tc = p[-WW];
            if (has_l) tl = p[-WW - 1];
            if (has_r) tr = p[-WW + 1];
        }
        if (has_b) {
            bc = p[WW];
            if (has_l) bl = p[WW - 1];
            if (has_r) br = p[WW + 1];
        }
        feat[c]             = mc;
        // sx = [[-1,0,1],[-2,0,2],[-1,0,1]] (cross-correlation)
        feat[STATE + c]     = (tr - tl) + 2.f * (mr - ml) + (br - bl);
        // sy = sx^T = [[-1,-2,-1],[0,0,0],[1,2,1]]
        feat[2 * STATE + c] = (bl + 2.f * bc + br) - (tl + 2.f * tc + tr);
    }

    #pragma unroll
    for (int d = 0; d < DNA_C; ++d) {
        feat[3 * STATE + d] = dna[(((size_t)b * DNA_C + d) * HH + y) * WW + xw];
    }

    // ---- MLP: upd = w2 @ relu(w1 @ feat) ----
    float upd[STATE];
    #pragma unroll
    for (int s = 0; s < STATE; ++s) upd[s] = 0.f;

    for (int o = 0; o < HID; o += 8) {     // dynamic outer loop, uniform weight addrs -> s_load
        float h[8];
        #pragma unroll
        for (int oo = 0; oo < 8; ++oo) {
            float acc = 0.f;
            #pragma unroll
            for (int c = 0; c < FAN1; ++c)
                acc = fmaf(w1[(o + oo) * FAN1 + c], feat[c], acc);
            h[oo] = fmaxf(acc, 0.f);
        }
        #pragma unroll
        for (int s = 0; s < STATE; ++s) {
            #pragma unroll
            for (int oo = 0; oo < 8; ++oo)
                upd[s] = fmaf(w2[s * HID + o + oo], h[oo], upd[s]);
        }
    }

    float* po = out + ((size_t)b * STATE * HH + y) * WW + xw;
    #pragma unroll
    for (int s = 0; s < STATE; ++s)
        po[(size_t)s * HH * WW] = upd[s];
}

extern "C" void kernel_launch(void* const* d_in, const int* in_sizes, int n_in,
                              void* d_out, int out_size, void* d_ws, size_t ws_size,
                              hipStream_t stream) {
    const float* x   = (const float*)d_in[0];
    const float* dna = (const float*)d_in[1];
    const float* w1  = (const float*)d_in[2];
    const float* w2  = (const float*)d_in[3];
    float* out = (float*)d_out;

    const int B = in_sizes[0] / (STATE * HH * WW);   // 16
    dim3 grid(B * HH);
    dim3 block(WW);
    update_net_f32<<<grid, block, 0, stream>>>(x, dna, w1, w2, out);
}

// Round 2
// 115.622 us; speedup vs baseline: 5.1234x; 5.1234x over previous
//
#include <hip/hip_runtime.h>

#define STATE 16
#define DNA_C 4
#define HID   128
#define FAN1  52
#define HH    256
#define WW    256

typedef unsigned short u16;
typedef unsigned int   u32;
typedef short bf8 __attribute__((ext_vector_type(8)));
typedef float f32x4 __attribute__((ext_vector_type(4)));

__device__ __forceinline__ u16 f2bf(float f) {
    union { float f; u32 u; } c; c.f = f;
    u32 u = c.u;
    return (u16)((u + 0x7FFFu + ((u >> 16) & 1u)) >> 16);   // RTNE
}
__device__ __forceinline__ u32 pack2(float a, float b) {
    return (u32)f2bf(a) | ((u32)f2bf(b) << 16);
}

__device__ __forceinline__ void sobel1(const float* __restrict__ p,
                                       bool hl, bool hr, bool ht, bool hb,
                                       float& mc, float& gx, float& gy) {
    float tl = 0.f, tc = 0.f, tr = 0.f;
    float ml = 0.f,           mr = 0.f;
    float bl = 0.f, bc = 0.f, br = 0.f;
    mc = p[0];
    if (hl) ml = p[-1];
    if (hr) mr = p[1];
    if (ht) {
        tc = p[-WW];
        if (hl) tl = p[-WW - 1];
        if (hr) tr = p[-WW + 1];
    }
    if (hb) {
        bc = p[WW];
        if (hl) bl = p[WW - 1];
        if (hr) br = p[WW + 1];
    }
    gx = (tr - tl) + 2.f * (mr - ml) + (br - bl);
    gy = (bl + 2.f * bc + br) - (tl + 2.f * tc + tr);
}

__global__ __launch_bounds__(256, 2) void update_net_mfma(
    const float* __restrict__ x,    // [B,16,256,256]
    const float* __restrict__ dna,  // [B,4,256,256]
    const float* __restrict__ w1,   // [128,52]
    const float* __restrict__ w2,   // [16,128]
    float* __restrict__ out)        // [B,16,256,256]
{
    // LDS (59.6 KB total -> 2 blocks/CU):
    //  w1h: w1 bf16 [128][72] (stride 144B, 16B-aligned) OVERLAID later by h [4 waves][16 px][136]
    //  w2 : [16][136] bf16
    //  feat: [256 px][72 k] bf16 (k=0..51 feat, 52..63 zero; stride 144B)
    __shared__ __align__(16) u16 w1h_lds[128 * 72];
    __shared__ __align__(16) u16 w2_lds[16 * 136];
    __shared__ __align__(16) u16 feat_lds[256 * 72];

    const int tid = threadIdx.x;
    const int row = blockIdx.x;
    const int b = row >> 8;
    const int y = row & 255;

    // ---- stage weights as bf16 ----
    for (int i = tid; i < 128 * FAN1; i += 256) {
        int r = i / FAN1, c = i - r * FAN1;
        w1h_lds[r * 72 + c] = f2bf(w1[i]);
    }
    for (int i = tid; i < 128 * 12; i += 256) {          // zero pad k=52..63
        int r = i / 12, c = FAN1 + (i - r * 12);
        w1h_lds[r * 72 + c] = 0;
    }
    for (int i = tid; i < STATE * HID; i += 256) {
        int r = i >> 7, c = i & 127;
        w2_lds[r * 136 + c] = f2bf(w2[i]);
    }

    // ---- per-thread features -> bf16 -> feat_lds[tid][k] ----
    {
        const int xw = tid;
        const bool hl = (xw > 0), hr = (xw < WW - 1);
        const bool ht = (y > 0),  hb = (y < HH - 1);
        const float* pb = x + (((size_t)b * STATE) * HH + y) * WW + xw;

        #pragma unroll
        for (int c = 0; c < STATE; c += 2) {
            float m0, g0x, g0y, m1, g1x, g1y;
            sobel1(pb + (size_t)c * HH * WW,       hl, hr, ht, hb, m0, g0x, g0y);
            sobel1(pb + (size_t)(c + 1) * HH * WW, hl, hr, ht, hb, m1, g1x, g1y);
            *(u32*)&feat_lds[tid * 72 + c]      = pack2(m0, m1);
            *(u32*)&feat_lds[tid * 72 + 16 + c] = pack2(g0x, g1x);
            *(u32*)&feat_lds[tid * 72 + 32 + c] = pack2(g0y, g1y);
        }
        const float* pd = dna + (((size_t)b * DNA_C) * HH + y) * WW + xw;
        float d0 = pd[0];
        float d1 = pd[(size_t)1 * HH * WW];
        float d2 = pd[(size_t)2 * HH * WW];
        float d3 = pd[(size_t)3 * HH * WW];
        *(u32*)&feat_lds[tid * 72 + 48] = pack2(d0, d1);
        *(u32*)&feat_lds[tid * 72 + 50] = pack2(d2, d3);
        // zero pad k=52..63
        *(u32*)&feat_lds[tid * 72 + 52] = 0;
        *(u32*)&feat_lds[tid * 72 + 54] = 0;
        *(uint4*)&feat_lds[tid * 72 + 56] = make_uint4(0, 0, 0, 0);
    }

    __syncthreads();

    // ---- load weight fragments into registers ----
    const int lane = tid & 63;
    const int wv   = tid >> 6;
    const int fj   = lane & 15;   // A-row / B-col / D-col
    const int fg   = lane >> 4;   // k-group (A/B), row-group (D)

    bf8 a1[8][2];                 // w1: 8 M-tiles x 2 K-tiles
    #pragma unroll
    for (int m = 0; m < 8; ++m) {
        #pragma unroll
        for (int kt = 0; kt < 2; ++kt)
            a1[m][kt] = *(const bf8*)&w1h_lds[(16 * m + fj) * 72 + 32 * kt + 8 * fg];
    }
    bf8 a2[4];                    // w2: 1 M-tile x 4 K-tiles
    #pragma unroll
    for (int kt = 0; kt < 4; ++kt)
        a2[kt] = *(const bf8*)&w2_lds[fj * 136 + 32 * kt + 8 * fg];

    __syncthreads();              // w1 region becomes h region below

    // ---- per-wave: 4 groups of 16 pixels ----
    #pragma unroll
    for (int g4 = 0; g4 < 4; ++g4) {
        const int pbase = wv * 64 + g4 * 16;
        const u16* fp = &feat_lds[(pbase + fj) * 72 + 8 * fg];
        bf8 b0 = *(const bf8*)fp;          // k =  8*fg .. +7
        bf8 b1 = *(const bf8*)(fp + 32);   // k = 32+8*fg .. +7

        f32x4 hacc[8];
        #pragma unroll
        for (int m = 0; m < 8; ++m) {
            f32x4 z = {0.f, 0.f, 0.f, 0.f};
            z = __builtin_amdgcn_mfma_f32_16x16x32_bf16(a1[m][0], b0, z, 0, 0, 0);
            hacc[m] = __builtin_amdgcn_mfma_f32_16x16x32_bf16(a1[m][1], b1, z, 0, 0, 0);
        }

        // relu + pack -> h_lds[wv][fj][k]; lane holds h rows 16m+4*fg+r, col fj
        u16* hrow = &w1h_lds[(wv * 16 + fj) * 136];
        #pragma unroll
        for (int m = 0; m < 8; ++m) {
            float h0 = fmaxf(hacc[m][0], 0.f), h1 = fmaxf(hacc[m][1], 0.f);
            float h2 = fmaxf(hacc[m][2], 0.f), h3 = fmaxf(hacc[m][3], 0.f);
            *(uint2*)&hrow[16 * m + 4 * fg] = make_uint2(pack2(h0, h1), pack2(h2, h3));
        }
        __asm volatile("s_waitcnt lgkmcnt(0)" ::: "memory");  // wave-local: writes visible to all 64 lanes

        f32x4 uacc = {0.f, 0.f, 0.f, 0.f};
        #pragma unroll
        for (int kt = 0; kt < 4; ++kt) {
            bf8 b2 = *(const bf8*)&hrow[32 * kt + 8 * fg];   // wrong row! need col fj's row
            b2 = *(const bf8*)&w1h_lds[(wv * 16 + fj) * 136 + 32 * kt + 8 * fg];
            uacc = __builtin_amdgcn_mfma_f32_16x16x32_bf16(a2[kt], b2, uacc, 0, 0, 0);
        }

        // store: lane holds upd[4*fg+r][pixel pbase+fj]
        const int xo = pbase + fj;
        float* po = out + (((size_t)b * STATE + 4 * fg) * HH + y) * WW + xo;
        #pragma unroll
        for (int r = 0; r < 4; ++r)
            po[(size_t)r * HH * WW] = uacc[r];
    }
}

extern "C" void kernel_launch(void* const* d_in, const int* in_sizes, int n_in,
                              void* d_out, int out_size, void* d_ws, size_t ws_size,
                              hipStream_t stream) {
    const float* x   = (const float*)d_in[0];
    const float* dna = (const float*)d_in[1];
    const float* w1  = (const float*)d_in[2];
    const float* w2  = (const float*)d_in[3];
    float* out = (float*)d_out;

    const int B = in_sizes[0] / (STATE * HH * WW);   // 16
    dim3 grid(B * HH);
    dim3 block(256);
    update_net_mfma<<<grid, block, 0, stream>>>(x, dna, w1, w2, out);
}

// Round 3
// 86.840 us; speedup vs baseline: 6.8215x; 1.3314x over previous
//
#include <hip/hip_runtime.h>
#include <hip/hip_bf16.h>

#define STATE 16
#define DNA_C 4
#define HID   128
#define FAN1  52
#define HH    256
#define WW    256
#define HW    (HH * WW)

typedef unsigned short u16;
typedef unsigned int   u32;
typedef short bf8 __attribute__((ext_vector_type(8)));
typedef float f32x4 __attribute__((ext_vector_type(4)));

__device__ __forceinline__ u32 pk(float a, float b) {
    __hip_bfloat162 t = __float22bfloat162_rn(make_float2(a, b));  // v_cvt_pk_bf16_f32
    union { __hip_bfloat162 h; u32 u; } c; c.h = t; return c.u;
}
__device__ __forceinline__ u16 f2bf(float f) {
    union { __hip_bfloat16 h; u16 u; } c; c.h = __float2bfloat16(f); return c.u;
}

__device__ __forceinline__ void sobel1(const float* __restrict__ p,
                                       bool hl, bool hr, bool ht, bool hb,
                                       float& mc, float& gx, float& gy) {
    float tl = 0.f, tc = 0.f, tr = 0.f;
    float ml = 0.f,           mr = 0.f;
    float bl = 0.f, bc = 0.f, br = 0.f;
    mc = p[0];
    if (hl) ml = p[-1];
    if (hr) mr = p[1];
    if (ht) {
        tc = p[-WW];
        if (hl) tl = p[-WW - 1];
        if (hr) tr = p[-WW + 1];
    }
    if (hb) {
        bc = p[WW];
        if (hl) bl = p[WW - 1];
        if (hr) br = p[WW + 1];
    }
    gx = (tr - tl) + 2.f * (mr - ml) + (br - bl);
    gy = (bl + 2.f * bc + br) - (tl + 2.f * tc + tr);
}

// ---- one-time (per launch) weight conversion: w1 [128][52]->bf16 [128][64] (zero-pad), w2 -> bf16 [16][128]
__global__ void prep_weights(const float* __restrict__ w1, const float* __restrict__ w2,
                             u16* __restrict__ wb) {
    int i = blockIdx.x * 256 + threadIdx.x;   // 0..10239
    if (i < 128 * 64) {
        int r = i >> 6, k = i & 63;
        wb[i] = (k < FAN1) ? f2bf(w1[r * FAN1 + k]) : (u16)0;
    } else {
        wb[i] = f2bf(w2[i - 128 * 64]);
    }
}

__global__ __launch_bounds__(256, 3) void update_net_mfma2(
    const float* __restrict__ x,    // [B,16,256,256]
    const float* __restrict__ dna,  // [B,4,256,256]
    const u16*   __restrict__ wb,   // bf16 weights: w1b[128][64], w2b[16][128]
    float* __restrict__ out)        // [B,16,256,256]
{
    // feat: [256 px][64 k] bf16, 128B rows, XOR-swizzled 16B chunks (chunk ^= row&7)
    // h   : per-wave [16 px][128 k] bf16, 256B rows, same swizzle on low 3 chunk bits
    __shared__ __align__(16) u16 feat_lds[256 * 64];   // 32 KB
    __shared__ __align__(16) u16 h_lds[4 * 16 * 128];  // 16 KB

    const int tid = threadIdx.x;
    const int row = blockIdx.x;
    const int b = row >> 8;
    const int y = row & 255;

    // ---- per-thread features -> bf16 -> swizzled feat_lds[tid][*] ----
    {
        const int xw = tid;
        const bool hl = (xw > 0), hr = (xw < WW - 1);
        const bool ht = (y > 0),  hb = (y < HH - 1);
        const float* pb = x + (((size_t)b * STATE) * HH + y) * WW + xw;
        const int sw = tid & 7;
        u16* frow = &feat_lds[tid * 64];

        #pragma unroll
        for (int half = 0; half < 2; ++half) {
            float fm[8], fgx[8], fgy[8];
            #pragma unroll
            for (int c = 0; c < 8; ++c)
                sobel1(pb + (size_t)(8 * half + c) * HW, hl, hr, ht, hb,
                       fm[c], fgx[c], fgy[c]);
            uint4 vm  = make_uint4(pk(fm[0], fm[1]),  pk(fm[2], fm[3]),
                                   pk(fm[4], fm[5]),  pk(fm[6], fm[7]));
            uint4 vgx = make_uint4(pk(fgx[0], fgx[1]), pk(fgx[2], fgx[3]),
                                   pk(fgx[4], fgx[5]), pk(fgx[6], fgx[7]));
            uint4 vgy = make_uint4(pk(fgy[0], fgy[1]), pk(fgy[2], fgy[3]),
                                   pk(fgy[4], fgy[5]), pk(fgy[6], fgy[7]));
            *(uint4*)&frow[8 * ((0 + half) ^ sw)] = vm;   // k 0-15  : x
            *(uint4*)&frow[8 * ((2 + half) ^ sw)] = vgx;  // k 16-31 : gx
            *(uint4*)&frow[8 * ((4 + half) ^ sw)] = vgy;  // k 32-47 : gy
        }
        const float* pd = dna + (((size_t)b * DNA_C) * HH + y) * WW + xw;
        float d0 = pd[0];
        float d1 = pd[(size_t)1 * HW];
        float d2 = pd[(size_t)2 * HW];
        float d3 = pd[(size_t)3 * HW];
        *(uint4*)&frow[8 * (6 ^ sw)] = make_uint4(pk(d0, d1), pk(d2, d3), 0u, 0u);
        *(uint4*)&frow[8 * (7 ^ sw)] = make_uint4(0u, 0u, 0u, 0u);
    }

    const int lane = tid & 63;
    const int wv   = tid >> 6;
    const int fj   = lane & 15;   // A-row / B-col / D-col
    const int fg   = lane >> 4;   // k-group (A/B), row-group (D)
    const int sfj  = fj & 7;

    // ---- weight fragments: global bf16 -> registers (L1-hot, shared by all waves) ----
    const u16* w1b = wb;             // [128][64]
    const u16* w2b = wb + 128 * 64;  // [16][128]
    bf8 a1[8][2];
    #pragma unroll
    for (int m = 0; m < 8; ++m) {
        #pragma unroll
        for (int kt = 0; kt < 2; ++kt)
            a1[m][kt] = *(const bf8*)&w1b[(16 * m + fj) * 64 + 32 * kt + 8 * fg];
    }
    bf8 a2[4];
    #pragma unroll
    for (int kt = 0; kt < 4; ++kt)
        a2[kt] = *(const bf8*)&w2b[fj * 128 + 32 * kt + 8 * fg];

    // feat writes -> reads are wave-local (wave wv reads rows [wv*64, wv*64+64) == its own tids)
    asm volatile("s_waitcnt lgkmcnt(0)" ::: "memory");

    u16* hwv = &h_lds[wv * 16 * 128];

    #pragma unroll
    for (int g4 = 0; g4 < 4; ++g4) {
        const int r = wv * 64 + g4 * 16 + fj;   // feat row; r&7 == sfj
        bf8 b0 = *(const bf8*)&feat_lds[r * 64 + 8 * ((0 + fg) ^ sfj)];
        bf8 b1 = *(const bf8*)&feat_lds[r * 64 + 8 * ((4 + fg) ^ sfj)];

        f32x4 hacc[8];
        #pragma unroll
        for (int m = 0; m < 8; ++m) {
            f32x4 z = {0.f, 0.f, 0.f, 0.f};
            z = __builtin_amdgcn_mfma_f32_16x16x32_bf16(a1[m][0], b0, z, 0, 0, 0);
            hacc[m] = __builtin_amdgcn_mfma_f32_16x16x32_bf16(a1[m][1], b1, z, 0, 0, 0);
        }

        // relu + pack; lane holds h[k=16m+4*fg+r][px=fj] -> h_lds[px=fj][k] swizzled
        #pragma unroll
        for (int m = 0; m < 8; ++m) {
            float h0 = fmaxf(hacc[m][0], 0.f), h1 = fmaxf(hacc[m][1], 0.f);
            float h2 = fmaxf(hacc[m][2], 0.f), h3 = fmaxf(hacc[m][3], 0.f);
            *(uint2*)&hwv[fj * 128 + 8 * ((2 * m + (fg >> 1)) ^ sfj) + 4 * (fg & 1)] =
                make_uint2(pk(h0, h1), pk(h2, h3));
        }
        asm volatile("s_waitcnt lgkmcnt(0)" ::: "memory");  // wave-local h exchange

        f32x4 uacc = {0.f, 0.f, 0.f, 0.f};
        #pragma unroll
        for (int kt = 0; kt < 4; ++kt) {
            bf8 b2 = *(const bf8*)&hwv[fj * 128 + 8 * ((4 * kt + fg) ^ sfj)];
            uacc = __builtin_amdgcn_mfma_f32_16x16x32_bf16(a2[kt], b2, uacc, 0, 0, 0);
        }

        // lane holds upd[s=4*fg+rr][pixel]
        const int xo = wv * 64 + g4 * 16 + fj;
        float* po = out + (((size_t)b * STATE + 4 * fg) * HH + y) * WW + xo;
        #pragma unroll
        for (int rr = 0; rr < 4; ++rr)
            po[(size_t)rr * HW] = uacc[rr];
    }
}

extern "C" void kernel_launch(void* const* d_in, const int* in_sizes, int n_in,
                              void* d_out, int out_size, void* d_ws, size_t ws_size,
                              hipStream_t stream) {
    const float* x   = (const float*)d_in[0];
    const float* dna = (const float*)d_in[1];
    const float* w1  = (const float*)d_in[2];
    const float* w2  = (const float*)d_in[3];
    float* out = (float*)d_out;
    u16* wb = (u16*)d_ws;   // 128*64 + 16*128 = 10240 u16 = 20 KB

    prep_weights<<<dim3(40), dim3(256), 0, stream>>>(w1, w2, wb);

    const int B = in_sizes[0] / (STATE * HH * WW);   // 16
    update_net_mfma2<<<dim3(B * HH), dim3(256), 0, stream>>>(x, dna, wb, out);
}